// Round 9
// baseline (297.685 us; speedup 1.0000x reference)
//
#include <hip/hip_runtime.h>

// ---------------------------------------------------------------------------
// DeepseekV3 MoE: T=2048 tokens, H=1024, E=16 experts (top-4), I=512, SI=1024
// 4 dispatches: prep (route + streaming fp32->bf16 convert, NO transpose),
// up-GEMM (dual B, silu*u), down-GEMM, combine.
// Round-9: FIX stage_bt double-counted k offset (caller pre-added
// (tid&31)*2*ldn AND stage_bt added bk*ldn -> read k = kt + 4*(tid&31);
// half the B-tile rows were from the wrong K rows -> absmax 7.97).
// Caller pointers now carry only the n offset; stage_bt owns the k term.
// ---------------------------------------------------------------------------

#define T_TOK 2048
#define H_DIM 1024
#define E_NUM 16
#define I_DIM 512
#define SI_DIM 1024

typedef __bf16 bf16x8 __attribute__((ext_vector_type(8)));
typedef short short8 __attribute__((ext_vector_type(8)));
typedef unsigned short ushort8 __attribute__((ext_vector_type(8)));
typedef float f32x4 __attribute__((ext_vector_type(4)));
typedef unsigned short u16;

struct alignas(8)  U16x4 { u16 x, y, z, w; };

__device__ __forceinline__ float bf2f(u16 u) {
    union { float f; unsigned int i; } v; v.i = ((unsigned int)u) << 16; return v.f;
}
__device__ __forceinline__ u16 f2bf(float f) {
    union { float f; unsigned int i; } v; v.f = f;
    unsigned int i = v.i;
    return (u16)((i + 0x7fffu + ((i >> 16) & 1u)) >> 16);   // RNE
}

#define GLOAD16(g, l)                                                          \
    __builtin_amdgcn_global_load_lds(                                          \
        (const __attribute__((address_space(1))) unsigned int*)(const void*)(g),\
        (__attribute__((address_space(3))) unsigned int*)(void*)(l), 16, 0, 0)

#define CNT(e) ((e) * 16)   // counts padded to one cacheline each

// ---------------------------------------------------------------------------
// K1: prep = streaming convert of 6 weight tensors (native layout) + routing.
// ---------------------------------------------------------------------------
__device__ __forceinline__ void route_block(
    const float* __restrict__ x, const float* __restrict__ gw,
    int* __restrict__ cnt, int* __restrict__ tok,
    int* __restrict__ slot, float* __restrict__ wgt, u16* __restrict__ xb,
    int blk)
{
    const int wid  = threadIdx.x >> 6;
    const int lane = threadIdx.x & 63;
    const int t    = blk * 4 + wid;

    const float* xp = x + (long)t * H_DIM;
    float xr[16];
#pragma unroll
    for (int j = 0; j < 16; ++j) xr[j] = xp[lane + 64 * j];

#pragma unroll
    for (int j = 0; j < 16; ++j) xb[(long)t * H_DIM + lane + 64 * j] = f2bf(xr[j]);

    float sc[E_NUM];
#pragma unroll
    for (int e = 0; e < E_NUM; ++e) {
        const float* gp = gw + e * H_DIM;
        float d = 0.f;
#pragma unroll
        for (int j = 0; j < 16; ++j) d += xr[j] * gp[lane + 64 * j];
#pragma unroll
        for (int off = 32; off; off >>= 1) d += __shfl_xor(d, off);
        sc[e] = 1.f / (1.f + expf(-d));      // sigmoid
    }

    // top-4, strict > so ties pick lowest index (matches jax top_k)
    float w[4]; int id[4];
    unsigned picked = 0;
    float sum = 0.f;
#pragma unroll
    for (int k = 0; k < 4; ++k) {
        float mv = -1.f; int mi = 0;
#pragma unroll
        for (int e = 0; e < E_NUM; ++e) {
            bool ok = !((picked >> e) & 1u) && (sc[e] > mv);
            mv = ok ? sc[e] : mv;
            mi = ok ? e : mi;
        }
        w[k] = mv; id[k] = mi; picked |= 1u << mi; sum += mv;
    }
    const float inv = 1.f / (sum + 1e-20f);

    if (lane == 0) {
#pragma unroll
        for (int k = 0; k < 4; ++k) {
            int pos = atomicAdd(&cnt[CNT(id[k])], 1);
            tok[id[k] * T_TOK + pos] = t;
            slot[t * 4 + k] = (id[k] << 16) | pos;
            wgt[t * 4 + k]  = w[k] * inv;
        }
    }
}

#define NCHUNK 7077888L   // total float4-chunks over the 6 weight tensors

__global__ __launch_bounds__(256) void prep_kernel(
    const float* __restrict__ x,  const float* __restrict__ gw,
    const float* __restrict__ eg, const float* __restrict__ eu,
    const float* __restrict__ ed, const float* __restrict__ sg,
    const float* __restrict__ su, const float* __restrict__ sd,
    u16* __restrict__ egb, u16* __restrict__ eub, u16* __restrict__ edb,
    u16* __restrict__ sgb, u16* __restrict__ sub, u16* __restrict__ sdb,
    int* __restrict__ cnt, int* __restrict__ tok,
    int* __restrict__ slot, float* __restrict__ wgt, u16* __restrict__ xb)
{
    const int b = blockIdx.x;
    if (b < 2048) {
        for (long c = (long)b * 256 + threadIdx.x; c < NCHUNK; c += 2048L * 256) {
            const float* src; u16* dst; long o;
            if      (c < 2097152L) { src = eg; dst = egb; o = c; }
            else if (c < 4194304L) { src = eu; dst = eub; o = c - 2097152L; }
            else if (c < 6291456L) { src = ed; dst = edb; o = c - 4194304L; }
            else if (c < 6553600L) { src = sg; dst = sgb; o = c - 6291456L; }
            else if (c < 6815744L) { src = su; dst = sub; o = c - 6553600L; }
            else                   { src = sd; dst = sdb; o = c - 6815744L; }
            float4 v = *(const float4*)&src[o * 4];
            U16x4 w = { f2bf(v.x), f2bf(v.y), f2bf(v.z), f2bf(v.w) };
            *(U16x4*)&dst[o * 4] = w;
        }
    } else {
        route_block(x, gw, cnt, tok, slot, wgt, xb, b - 2048);
    }
}

// ---------------------------------------------------------------------------
// B-tile staging: native [k][n] bf16 rows -> transposed chunk-XOR-swizzled
// LDS tile. Thread: p=tid&31 -> k=2p,2p+1 (stage_bt adds BOTH k terms;
// caller pointer carries ONLY the n offset + kt*ldn). nset=tid>>5 -> 8 n's.
// Loads two 16B row segments, packs (k,k+1) u16 pairs, 8 ds_write_b32
// (each wave instr hits all 32 banks exactly twice: free).
// LDS elem off(n,k) = n*64 + (((k>>3) ^ (n&7))<<3) + (k&7)  [matches reads]
// ---------------------------------------------------------------------------
__device__ __forceinline__ void stage_bt(
    u16* __restrict__ lds, const u16* __restrict__ Wbase,
    long ldn, int tid, int nbase)
{
    const int p    = tid & 31;
    const int bk   = p * 2;
    const int bn   = nbase + (tid >> 5) * 8;
    const ushort8 v0 = *(const ushort8*)(Wbase + (long)bk * ldn);
    const ushort8 v1 = *(const ushort8*)(Wbase + (long)(bk + 1) * ldn);
    const int cp   = bk >> 3;
    const int klo  = bk & 7;
#pragma unroll
    for (int j = 0; j < 8; ++j) {
        int n   = bn + j;
        int off = n * 64 + ((cp ^ (n & 7)) << 3) + klo;
        *(unsigned int*)&lds[off] =
            (unsigned int)v0[j] | ((unsigned int)v1[j] << 16);
    }
}

// ---------------------------------------------------------------------------
// K2: up-GEMM. Tile 128x64, BK=64, 4 waves (2x2, wave 64x32), DUAL B
// (gate+up), silu(g)*u epilogue. A via global_load_lds (pre-swizzled src);
// B via stage_bt from NATIVE-layout bf16 weights. Compact grid decode,
// m-fastest per expert, bijective XCD chunk swizzle.
// ---------------------------------------------------------------------------
__global__ __launch_bounds__(256, 3) void gemm_up(
    const u16* __restrict__ xb,
    const u16* __restrict__ Wr1, const u16* __restrict__ Wr2,
    const u16* __restrict__ Ws1, const u16* __restrict__ Ws2,
    u16* __restrict__ actR, u16* __restrict__ actS,
    const int* __restrict__ cnt, const int* __restrict__ tok)
{
    constexpr int NWG = 896, CPX = NWG / 8;
    const int bswz = blockIdx.x;
    int j = (bswz & 7) * CPX + (bswz >> 3);   // XCD-chunk swizzle (bijective)

    // ---- compact work decode ----
    bool routed = false;
    int e = 0, mb = 0, nb = 0, M = 0, rbase = 0;
    {
        int acc = 0, found = 0;
        for (int i = 0; i < E_NUM && !found; ++i) {
            int m   = cnt[CNT(i)];
            int nbk = (m + 127) >> 7;          // ceil(M/128) m-tiles
            int bl  = nbk * 8;                 // x 8 n-tiles (N=512)
            if (j < bl) { routed = true; e = i; M = m; mb = j % nbk; nb = j / nbk; found = 1; }
            else        { j -= bl; acc += m; }
        }
        rbase = acc;
        if (!routed) {
            if (j >= 256) return;              // shared: 16 mb x 16 nb
            M = T_TOK; mb = j & 15; nb = j >> 4;
        }
    }

    const u16 *B1p, *B2p;
    long ldn;
    int  Ntot;
    if (routed) {
        Ntot = I_DIM; ldn = I_DIM;
        B1p  = Wr1 + (long)e * (512L * 1024L);
        B2p  = Wr2 + (long)e * (512L * 1024L);
    } else {
        Ntot = SI_DIM; ldn = SI_DIM;
        B1p = Ws1; B2p = Ws2;
    }
    const int m0 = mb * 128;
    const int n0 = nb * 64;
    const int K  = H_DIM;

    __shared__ __attribute__((aligned(16))) u16 sA[128 * 64];
    __shared__ __attribute__((aligned(16))) u16 sB1[64 * 64];
    __shared__ __attribute__((aligned(16))) u16 sB2[64 * 64];

    const int tid  = threadIdx.x;
    const int lane = tid & 63;
    const int wid  = tid >> 6;
    const int wr   = wid >> 1;
    const int wc   = wid & 1;

    // A staging sources (pre-swizzled global chunks -> linear LDS)
    const u16* aptr[4];
#pragma unroll
    for (int i = 0; i < 4; ++i) {
        int q = i * 256 + tid;
        int row = q >> 3, s = q & 7;
        int r = m0 + row; if (r >= M) r = M - 1;          // clamp; masked at C
        long grow = routed ? (long)tok[e * T_TOK + r] : (long)r;
        aptr[i] = xb + grow * (long)K + ((s ^ (row & 7)) << 3);
    }
    // B staging base pointers: ONLY the n offset (k term lives in stage_bt)
    const u16* b1row = B1p + n0 + (tid >> 5) * 8;
    const u16* b2row = B2p + n0 + (tid >> 5) * 8;

    f32x4 accG[4][2], accU[4][2];
#pragma unroll
    for (int i = 0; i < 4; ++i)
#pragma unroll
        for (int jj = 0; jj < 2; ++jj) {
            accG[i][jj] = (f32x4){0.f, 0.f, 0.f, 0.f};
            accU[i][jj] = (f32x4){0.f, 0.f, 0.f, 0.f};
        }

    for (int kt = 0; kt < K; kt += 64) {
        __syncthreads();                   // previous tile fully consumed
#pragma unroll
        for (int i = 0; i < 4; ++i) GLOAD16(aptr[i] + kt, &sA[(i * 256 + tid) * 8]);
        stage_bt(sB1, b1row + (long)kt * ldn, ldn, tid, 0);
        stage_bt(sB2, b2row + (long)kt * ldn, ldn, tid, 0);
        asm volatile("s_waitcnt vmcnt(0)" ::: "memory");
        __syncthreads();

#pragma unroll
        for (int ks = 0; ks < 2; ++ks) {
            bf16x8 a[4], bg[2], bu[2];
#pragma unroll
            for (int mf = 0; mf < 4; ++mf) {
                int row = wr * 64 + mf * 16 + (lane & 15);
                int c   = ks * 4 + (lane >> 4);
                a[mf] = __builtin_bit_cast(bf16x8,
                    *(const short8*)&sA[row * 64 + ((c ^ (row & 7)) << 3)]);
            }
#pragma unroll
            for (int nf = 0; nf < 2; ++nf) {
                int row = wc * 32 + nf * 16 + (lane & 15);
                int c   = ks * 4 + (lane >> 4);
                int o   = row * 64 + ((c ^ (row & 7)) << 3);
                bg[nf] = __builtin_bit_cast(bf16x8, *(const short8*)&sB1[o]);
                bu[nf] = __builtin_bit_cast(bf16x8, *(const short8*)&sB2[o]);
            }
#pragma unroll
            for (int mf = 0; mf < 4; ++mf)
#pragma unroll
                for (int nf = 0; nf < 2; ++nf) {
                    accG[mf][nf] = __builtin_amdgcn_mfma_f32_16x16x32_bf16(
                        a[mf], bg[nf], accG[mf][nf], 0, 0, 0);
                    accU[mf][nf] = __builtin_amdgcn_mfma_f32_16x16x32_bf16(
                        a[mf], bu[nf], accU[mf][nf], 0, 0, 0);
                }
        }
    }

    // epilogue: C/D layout col = lane&15, row = (lane>>4)*4 + reg  [m89]
    u16* outp = routed ? actR : actS;
#pragma unroll
    for (int mf = 0; mf < 4; ++mf)
#pragma unroll
        for (int nf = 0; nf < 2; ++nf)
#pragma unroll
            for (int r = 0; r < 4; ++r) {
                int row = m0 + wr * 64 + mf * 16 + (lane >> 4) * 4 + r;
                if (row >= M) continue;
                int col = n0 + wc * 32 + nf * 16 + (lane & 15);
                float g = accG[mf][nf][r];
                float v = g / (1.f + expf(-g)) * accU[mf][nf][r];   // silu(g)*u
                long orow = routed ? (long)(rbase + row) : (long)row;
                outp[orow * Ntot + col] = f2bf(v);
            }
}

// ---------------------------------------------------------------------------
// K3: down-GEMM. Tile 128x128, BK=64, 4 waves (2x2, wave 64x64), single B
// staged from NATIVE ed/sd (two stage_bt halves). Compact grid.
// Routed: actR @ ed -> pair (bf16). Shared: actS @ sd -> out (fp32).
// ---------------------------------------------------------------------------
__global__ __launch_bounds__(256, 3) void gemm_down(
    const u16* __restrict__ actR, const u16* __restrict__ actS,
    const u16* __restrict__ Wr,   const u16* __restrict__ Ws,
    u16* __restrict__ pair, float* __restrict__ out,
    const int* __restrict__ cnt)
{
    constexpr int NWG = 760, CPX = NWG / 8;
    const int bswz = blockIdx.x;
    int j = (bswz & 7) * CPX + (bswz >> 3);

    bool routed = false;
    int e = 0, mb = 0, nb = 0, M = 0, rbase = 0;
    {
        int acc = 0, found = 0;
        for (int i = 0; i < E_NUM && !found; ++i) {
            int m   = cnt[CNT(i)];
            int nbk = (m + 127) >> 7;
            int bl  = nbk * 8;                 // 8 n-tiles (N=1024, 128-tile)
            if (j < bl) { routed = true; e = i; M = m; mb = j % nbk; nb = j / nbk; found = 1; }
            else        { j -= bl; acc += m; }
        }
        rbase = acc;
        if (!routed) {
            if (j >= 128) return;              // shared: 16 mb x 8 nb
            M = T_TOK; mb = j & 15; nb = j >> 4;
        }
    }

    int K;
    const u16 *Ap, *Bp;
    if (routed) {
        K  = I_DIM;
        Ap = actR;
        Bp = Wr + (long)e * (512L * 1024L);
    } else {
        K = SI_DIM;
        Ap = actS; Bp = Ws;
    }
    const long ldn = H_DIM;                    // ed:[I][H], sd:[SI][H]
    const int m0 = mb * 128;
    const int n0 = nb * 128;

    __shared__ __attribute__((aligned(16))) u16 sA[128 * 64];
    __shared__ __attribute__((aligned(16))) u16 sB[128 * 64];

    const int tid  = threadIdx.x;
    const int lane = tid & 63;
    const int wid  = tid >> 6;
    const int wr   = wid >> 1;
    const int wc   = wid & 1;

    const u16* aptr[4];
#pragma unroll
    for (int i = 0; i < 4; ++i) {
        int q = i * 256 + tid;
        int row = q >> 3, s = q & 7;
        int r = m0 + row; if (r >= M) r = M - 1;
        long grow = routed ? (long)(rbase + r) : (long)r;
        aptr[i] = Ap + grow * (long)K + ((s ^ (row & 7)) << 3);
    }
    // B staging base pointer: ONLY the n offset (k term lives in stage_bt)
    const u16* brow = Bp + n0 + (tid >> 5) * 8;

    f32x4 acc[4][4];
#pragma unroll
    for (int i = 0; i < 4; ++i)
#pragma unroll
        for (int jj = 0; jj < 4; ++jj) acc[i][jj] = (f32x4){0.f, 0.f, 0.f, 0.f};

    for (int kt = 0; kt < K; kt += 64) {
        __syncthreads();
#pragma unroll
        for (int i = 0; i < 4; ++i) GLOAD16(aptr[i] + kt, &sA[(i * 256 + tid) * 8]);
        stage_bt(sB, brow + (long)kt * ldn, ldn, tid, 0);       // n 0..63
        stage_bt(sB, brow + (long)kt * ldn + 64, ldn, tid, 64); // n 64..127
        asm volatile("s_waitcnt vmcnt(0)" ::: "memory");
        __syncthreads();

#pragma unroll
        for (int ks = 0; ks < 2; ++ks) {
            bf16x8 a[4], b[4];
#pragma unroll
            for (int mf = 0; mf < 4; ++mf) {
                int row = wr * 64 + mf * 16 + (lane & 15);
                int c   = ks * 4 + (lane >> 4);
                a[mf] = __builtin_bit_cast(bf16x8,
                    *(const short8*)&sA[row * 64 + ((c ^ (row & 7)) << 3)]);
            }
#pragma unroll
            for (int nf = 0; nf < 4; ++nf) {
                int row = wc * 64 + nf * 16 + (lane & 15);
                int c   = ks * 4 + (lane >> 4);
                b[nf] = __builtin_bit_cast(bf16x8,
                    *(const short8*)&sB[row * 64 + ((c ^ (row & 7)) << 3)]);
            }
#pragma unroll
            for (int mf = 0; mf < 4; ++mf)
#pragma unroll
                for (int nf = 0; nf < 4; ++nf)
                    acc[mf][nf] = __builtin_amdgcn_mfma_f32_16x16x32_bf16(
                        a[mf], b[nf], acc[mf][nf], 0, 0, 0);
        }
    }

#pragma unroll
    for (int mf = 0; mf < 4; ++mf)
#pragma unroll
        for (int nf = 0; nf < 4; ++nf)
#pragma unroll
            for (int r = 0; r < 4; ++r) {
                int row = m0 + wr * 64 + mf * 16 + (lane >> 4) * 4 + r;
                if (row >= M) continue;
                int col = n0 + wc * 64 + nf * 16 + (lane & 15);
                float v = acc[mf][nf][r];
                if (routed) pair[(long)(rbase + row) * H_DIM + col] = f2bf(v);
                else        out[(long)row * H_DIM + col] = v;
            }
}

// ---------------------------------------------------------------------------
// K4: combine. out[t] (already = shared_out) += sum_k w_k * pair[eb+pos].
// ---------------------------------------------------------------------------
__global__ __launch_bounds__(256) void combine_kernel(
    float* __restrict__ out, const u16* __restrict__ pair,
    const int* __restrict__ slot, const float* __restrict__ wgt,
    const int* __restrict__ cnt)
{
    __shared__ int eb_s[E_NUM];
    if (threadIdx.x < E_NUM) {
        int s = 0;
        for (int i = 0; i < E_NUM; ++i) s += (i < (int)threadIdx.x) ? cnt[CNT(i)] : 0;
        eb_s[threadIdx.x] = s;
    }
    __syncthreads();

    const int t = blockIdx.x;
    const int c = threadIdx.x * 4;
    float4 o = *(float4*)&out[(long)t * H_DIM + c];
#pragma unroll
    for (int k = 0; k < 4; ++k) {
        int s = slot[t * 4 + k];
        int e = s >> 16, pos = s & 0xffff;
        float w = wgt[t * 4 + k];
        const u16* pr = pair + (long)(eb_s[e] + pos) * H_DIM + c;
        U16x4 pv = *(const U16x4*)pr;
        o.x += w * bf2f(pv.x);
        o.y += w * bf2f(pv.y);
        o.z += w * bf2f(pv.z);
        o.w += w * bf2f(pv.w);
    }
    *(float4*)&out[(long)t * H_DIM + c] = o;
}

// ---------------------------------------------------------------------------
extern "C" void kernel_launch(void* const* d_in, const int* in_sizes, int n_in,
                              void* d_out, int out_size, void* d_ws, size_t ws_size,
                              hipStream_t stream)
{
    const float* x  = (const float*)d_in[0];
    const float* gw = (const float*)d_in[1];
    const float* eg = (const float*)d_in[2];
    const float* eu = (const float*)d_in[3];
    const float* ed = (const float*)d_in[4];
    const float* sg = (const float*)d_in[5];
    const float* su = (const float*)d_in[6];
    const float* sd = (const float*)d_in[7];
    float* out = (float*)d_out;

    unsigned char* w = (unsigned char*)d_ws;
    size_t off = 0;
    auto alloc = [&](size_t b) -> void* {
        off = (off + 255) & ~(size_t)255;
        void* p = w + off; off += b; return p;
    };
    int*   cnt  = (int*)  alloc(256 * 4);
    int*   tok  = (int*)  alloc((size_t)E_NUM * T_TOK * 4);
    int*   slot = (int*)  alloc((size_t)T_TOK * 4 * 4);
    float* wgt  = (float*)alloc((size_t)T_TOK * 4 * 4);
    u16*   xb   = (u16*)  alloc((size_t)T_TOK * H_DIM * 2);
    u16*   egb  = (u16*)  alloc((size_t)E_NUM * H_DIM * I_DIM * 2);   // native [h][i]
    u16*   eub  = (u16*)  alloc((size_t)E_NUM * H_DIM * I_DIM * 2);
    u16*   edb  = (u16*)  alloc((size_t)E_NUM * I_DIM * H_DIM * 2);   // native [i][h]
    u16*   sgb  = (u16*)  alloc((size_t)H_DIM * SI_DIM * 2);
    u16*   sub  = (u16*)  alloc((size_t)H_DIM * SI_DIM * 2);
    u16*   sdb  = (u16*)  alloc((size_t)SI_DIM * H_DIM * 2);
    u16*   actR = (u16*)  alloc((size_t)T_TOK * 4 * I_DIM * 2);  // 8192 x 512
    u16*   actS = (u16*)  alloc((size_t)T_TOK * SI_DIM * 2);     // 2048 x 1024
    u16*   pair = (u16*)  alloc((size_t)T_TOK * 4 * H_DIM * 2);  // 8192 x 1024

    hipMemsetAsync(cnt, 0, 256 * 4, stream);

    prep_kernel<<<2560, 256, 0, stream>>>(x, gw, eg, eu, ed, sg, su, sd,
                                          egb, eub, edb, sgb, sub, sdb,
                                          cnt, tok, slot, wgt, xb);
    gemm_up<<<896, 256, 0, stream>>>(xb, egb, eub, sgb, sub,
                                     actR, actS, cnt, tok);
    gemm_down<<<760, 256, 0, stream>>>(actR, actS, edb, sdb,
                                       pair, out, cnt);
    combine_kernel<<<T_TOK, 256, 0, stream>>>(out, pair, slot, wgt, cnt);
}